// Round 7
// baseline (97.617 us; speedup 1.0000x reference)
//
#include <hip/hip_runtime.h>

#define ROWS 16384
#define COLS 4096
#define MAXQF 15.0f

// One block (256 threads) per row. Each thread loads 16 elements (4x float4)
// into registers, block-reduces min/max, then quantizes from registers.
// x is read exactly once from HBM; q written once. Memory-bound.
//
// Numerics hypothesis (round-6): expected was produced by XLA-CPU with
// fast-math. Three divides, each either CR-div (d) or recip-mul (m):
//   scale=(max-min)/15 : const divisor -> LLVM 'arcp' rewrites to
//                        (max-min) * f32(1/15)            [m]
//   q = x/scale        : loop-invariant divisor in the fused elementwise
//                        loop -> hoisted recip: x * CR(1/scale)  [m]
//   zeros = -min/scale : standalone scalar fdiv, single use -> stays a
//                        CR divide                        [d]
// Tried and failed: (d,d,d) r1/r3, (d,m,d) r5, (m,d,d) r6, f64 r4 — all
// absmax=1.0 tie-flips. This round: (m,m,d), the unique untested plausible
// combo. All per-row scalars go through f64 so hipcc flags can't perturb
// them (double-rounding flip probability negligible).
__global__ __launch_bounds__(256) void asym_quant_kernel(
    const float* __restrict__ x,
    float* __restrict__ q,
    float* __restrict__ scale_out,
    float* __restrict__ zeros_out) {
  const int row = blockIdx.x;
  const int tid = threadIdx.x;

  const float4* __restrict__ xrow =
      reinterpret_cast<const float4*>(x + (size_t)row * COLS);

  float4 v[4];
#pragma unroll
  for (int i = 0; i < 4; ++i) v[i] = xrow[tid + 256 * i];

  float mn = v[0].x;
  float mx = v[0].x;
#pragma unroll
  for (int i = 0; i < 4; ++i) {
    mn = fminf(mn, fminf(fminf(v[i].x, v[i].y), fminf(v[i].z, v[i].w)));
    mx = fmaxf(mx, fmaxf(fmaxf(v[i].x, v[i].y), fmaxf(v[i].z, v[i].w)));
  }

  // 64-lane wave butterfly reduce (wave = 64 on CDNA).
#pragma unroll
  for (int off = 1; off < 64; off <<= 1) {
    mn = fminf(mn, __shfl_xor(mn, off));
    mx = fmaxf(mx, __shfl_xor(mx, off));
  }

  // Cross-wave combine (4 waves per block).
  __shared__ float smn[4];
  __shared__ float smx[4];
  const int wave = tid >> 6;
  if ((tid & 63) == 0) {
    smn[wave] = mn;
    smx[wave] = mx;
  }
  __syncthreads();
  mn = fminf(fminf(smn[0], smn[1]), fminf(smn[2], smn[3]));
  mx = fmaxf(fmaxf(smx[0], smx[1]), fmaxf(smx[2], smx[3]));

  // [m] scale = (max-min) * f32(1/15), f32(1/15) = 0x3D888889.
  const float s = (mx - mn) * 0.066666670143604278564453125f;
  // [m] inv = CR_f32(1/scale), via f64 (flag-proof correctly-rounded).
  const float inv = (float)(1.0 / (double)s);
  // [d] zeros = round(CR_f32(-min/scale)), via f64 (flag-proof CR).
  const float z = rintf((float)((double)(0.0f - mn) / (double)s));

  if (tid == 0) {
    scale_out[row] = s;
    zeros_out[row] = z;  // integer in [0,15], exact in fp16; stored as f32
  }

  float4* __restrict__ qrow = reinterpret_cast<float4*>(q + (size_t)row * COLS);
#pragma unroll
  for (int i = 0; i < 4; ++i) {
    float4 o;
    // [m] q = clip(round(x * inv) + z, 0, 15): f32 mul is always CR;
    // v_rndne_f32 = half-even = np/XLA round-nearest-even.
    o.x = fminf(fmaxf(rintf(v[i].x * inv) + z, 0.0f), MAXQF);
    o.y = fminf(fmaxf(rintf(v[i].y * inv) + z, 0.0f), MAXQF);
    o.z = fminf(fmaxf(rintf(v[i].z * inv) + z, 0.0f), MAXQF);
    o.w = fminf(fmaxf(rintf(v[i].w * inv) + z, 0.0f), MAXQF);
    qrow[tid + 256 * i] = o;
  }
}

extern "C" void kernel_launch(void* const* d_in, const int* in_sizes, int n_in,
                              void* d_out, int out_size, void* d_ws, size_t ws_size,
                              hipStream_t stream) {
  const float* x = (const float*)d_in[0];
  float* out = (float*)d_out;

  // Tuple output, concatenated flat in return order:
  //   q:     ROWS*COLS f32
  //   scale: ROWS      f32
  //   zeros: ROWS      f32 (fp16-exact integers)
  float* q = out;
  float* scale = out + (size_t)ROWS * COLS;
  float* zeros = scale + ROWS;

  asym_quant_kernel<<<ROWS, 256, 0, stream>>>(x, q, scale, zeros);
}

// Round 9
// 89.246 us; speedup vs baseline: 1.0938x; 1.0938x over previous
//
#include <hip/hip_runtime.h>

#define ROWS 16384
#define COLS 4096
#define MAXQF 15.0f

// Native clang vector type — __builtin_nontemporal_load/store requires a
// pointer to scalar/vector-of-scalar, not HIP's float4 struct. Same 16-B
// layout and alignment.
typedef float f32x4 __attribute__((ext_vector_type(4)));

// One block (256 threads) per row. Each thread loads 16 elements (4x 16B)
// into registers, block-reduces min/max, then quantizes from registers.
// x is read exactly once from HBM; q written once. Memory-bound.
//
// Numerics (VERIFIED passing, round 7 — do not perturb): the jax/XLA
// expected corresponds to the (m,m,d) divide lowering:
//   scale = (max-min) * f32(1/15)          [recip-mul, 0x3D888889]
//   q     = round(x * CR_f32(1/scale)) + z [hoisted reciprocal multiply]
//   zeros = round(CR_f32(-min/scale))      [true correctly-rounded divide]
// Per-row scalars go through f64 to be compile-flag-proof.
//
// Round 9 change: nontemporal (nt) loads/stores via ext_vector_type —
// both big tensors are read-once/write-once, zero reuse; nt bypasses L2
// allocation (harness fill kernels sustain 6.9 TB/s vs our 5.5).
__global__ __launch_bounds__(256) void asym_quant_kernel(
    const float* __restrict__ x,
    float* __restrict__ q,
    float* __restrict__ scale_out,
    float* __restrict__ zeros_out) {
  const int row = blockIdx.x;
  const int tid = threadIdx.x;

  const f32x4* __restrict__ xrow =
      reinterpret_cast<const f32x4*>(x + (size_t)row * COLS);

  f32x4 v[4];
#pragma unroll
  for (int i = 0; i < 4; ++i)
    v[i] = __builtin_nontemporal_load(xrow + tid + 256 * i);

  float mn = v[0].x;
  float mx = v[0].x;
#pragma unroll
  for (int i = 0; i < 4; ++i) {
    mn = fminf(mn, fminf(fminf(v[i].x, v[i].y), fminf(v[i].z, v[i].w)));
    mx = fmaxf(mx, fmaxf(fmaxf(v[i].x, v[i].y), fmaxf(v[i].z, v[i].w)));
  }

  // 64-lane wave butterfly reduce (wave = 64 on CDNA).
#pragma unroll
  for (int off = 1; off < 64; off <<= 1) {
    mn = fminf(mn, __shfl_xor(mn, off));
    mx = fmaxf(mx, __shfl_xor(mx, off));
  }

  // Cross-wave combine (4 waves per block).
  __shared__ float smn[4];
  __shared__ float smx[4];
  const int wave = tid >> 6;
  if ((tid & 63) == 0) {
    smn[wave] = mn;
    smx[wave] = mx;
  }
  __syncthreads();
  mn = fminf(fminf(smn[0], smn[1]), fminf(smn[2], smn[3]));
  mx = fmaxf(fmaxf(smx[0], smx[1]), fmaxf(smx[2], smx[3]));

  // [m] scale = (max-min) * f32(1/15), f32(1/15) = 0x3D888889.
  const float s = (mx - mn) * 0.066666670143604278564453125f;
  // [m] inv = CR_f32(1/scale), via f64 (flag-proof correctly-rounded).
  const float inv = (float)(1.0 / (double)s);
  // [d] zeros = round(CR_f32(-min/scale)), via f64 (flag-proof CR).
  const float z = rintf((float)((double)(0.0f - mn) / (double)s));

  if (tid == 0) {
    scale_out[row] = s;
    zeros_out[row] = z;  // integer in [0,15], exact in fp16; stored as f32
  }

  f32x4* __restrict__ qrow = reinterpret_cast<f32x4*>(q + (size_t)row * COLS);
#pragma unroll
  for (int i = 0; i < 4; ++i) {
    f32x4 o;
    // [m] q = clip(round(x * inv) + z, 0, 15): f32 mul is always CR;
    // v_rndne_f32 = half-even = np/XLA round-nearest-even.
    o.x = fminf(fmaxf(rintf(v[i].x * inv) + z, 0.0f), MAXQF);
    o.y = fminf(fmaxf(rintf(v[i].y * inv) + z, 0.0f), MAXQF);
    o.z = fminf(fmaxf(rintf(v[i].z * inv) + z, 0.0f), MAXQF);
    o.w = fminf(fmaxf(rintf(v[i].w * inv) + z, 0.0f), MAXQF);
    __builtin_nontemporal_store(o, qrow + tid + 256 * i);
  }
}

extern "C" void kernel_launch(void* const* d_in, const int* in_sizes, int n_in,
                              void* d_out, int out_size, void* d_ws, size_t ws_size,
                              hipStream_t stream) {
  const float* x = (const float*)d_in[0];
  float* out = (float*)d_out;

  // Tuple output, concatenated flat in return order:
  //   q:     ROWS*COLS f32
  //   scale: ROWS      f32
  //   zeros: ROWS      f32 (fp16-exact integers)
  float* q = out;
  float* scale = out + (size_t)ROWS * COLS;
  float* zeros = scale + ROWS;

  asym_quant_kernel<<<ROWS, 256, 0, stream>>>(x, q, scale, zeros);
}